// Round 9
// baseline (77.582 us; speedup 1.0000x reference)
//
#include <hip/hip_runtime.h>
#include <hip/hip_bf16.h>
#include <math.h>

#define NB 32
#define NL 128
#define ND 128

typedef __attribute__((ext_vector_type(8))) short bf16x8;
typedef __attribute__((ext_vector_type(4))) float f32x4;

union F4  { float4 v; float f[4]; };
union BF8 { bf16x8 v; ushort u[8]; };

__device__ inline ushort f2bf(float f) {
    __hip_bfloat16 h = __float2bfloat16(f);
    union { __hip_bfloat16 h; ushort u; } c; c.h = h; return c.u;
}
__device__ inline float bf2f(ushort u) {
    union { unsigned int i; float f; } c; c.i = ((unsigned int)u) << 16; return c.f;
}
// split f into bf16 hi + bf16 lo (lo = fp32 residual, re-rounded)
__device__ inline short2 bsplit(float f) {
    ushort hu = f2bf(f);
    short2 r;
    r.x = (short)hu;
    r.y = (short)f2bf(f - bf2f(hu));
    return r;
}

// ---------------------------------------------------------------------------
// k_wsplit: pre-split all four W mats fp32 -> bf16 hi/lo global arrays
// [mat][d][k] (mat order: Wr1, Wi1, Wr2, Wi2 = main kernel's mat index).
// Grid 64 = 4 mats x 16 chunks. Block 256. Fully coalesced.
// ---------------------------------------------------------------------------
__global__ __launch_bounds__(256) void k_wsplit(
    const float* __restrict__ Wr1, const float* __restrict__ Wi1,
    const float* __restrict__ Wr2, const float* __restrict__ Wi2,
    ushort* __restrict__ whg, ushort* __restrict__ wlg)
{
    const int mat   = blockIdx.x >> 4;
    const int chunk = blockIdx.x & 15;
    const float* W = (mat == 0) ? Wr1 : (mat == 1) ? Wi1 : (mat == 2) ? Wr2 : Wi2;
    const int idx = chunk * 1024 + threadIdx.x * 4;
    F4 v; v.v = *(const float4*)&W[idx];
    short2 s0 = bsplit(v.f[0]), s1 = bsplit(v.f[1]);
    short2 s2 = bsplit(v.f[2]), s3 = bsplit(v.f[3]);
    ushort4 h = {(ushort)s0.x, (ushort)s1.x, (ushort)s2.x, (ushort)s3.x};
    ushort4 l = {(ushort)s0.y, (ushort)s1.y, (ushort)s2.y, (ushort)s3.y};
    *(ushort4*)&whg[mat * 16384 + idx] = h;
    *(ushort4*)&wlg[mat * 16384 + idx] = l;
}

// ---------------------------------------------------------------------------
// k_fused: one block per batch (grid 32, block 512 = 8 waves).
// Proj phase: NO LDS, NO barriers. A-frags (X) loaded fp32 from global +
//   split in-reg (lane pattern = row w*16+l15, k = ks*32+(lane>>4)*8 — the
//   HW-verified 16x16x32 ABt fragment pattern, same bytes the r8 LDS
//   round-trip produced). B-frags (W) loaded pre-split bf16 hi/lo from
//   k_wsplit's arrays. Split-bf16 MFMA: XhWh + XhWl + XlWh.
// Epilogue: bias; logit partials (16-lane shfl); y2/y3 -> bf16 G [d][l] in
//   LDS (XOR-swizzled, r8-verified layout).
// Softmax: wave-parallel -> wfl = full weight (not sqrt).
// Gram phase: A-side = w (.) G scaled IN-REGISTER; B-side = raw G from LDS.
//   Wave = (term = w>>2, m-tile pair (w&3)*2+{0,1}) -> B-reads shared
//   across 2 m-tiles. Mr = (wr.r2)r2^T - (wr.i2)i2^T ;
//   Mi = (wi.i2)r2^T + (wi.r2)i2^T. C-write mapping r4/r8-verified.
// LDS: G 64K + lgs 1K + wfl 1K + wred = ~66 KB dynamic.
// ---------------------------------------------------------------------------
__global__ __launch_bounds__(512, 2) void k_fused(
    const float* __restrict__ xr, const float* __restrict__ xi,
    const ushort* __restrict__ whg, const ushort* __restrict__ wlg,
    const float* __restrict__ br1, const float* __restrict__ bi1,
    const float* __restrict__ br2, const float* __restrict__ bi2,
    float* __restrict__ out)
{
    extern __shared__ char L[];
    char*  Gm   = L;                       // 2 x 32768: bf16 [d][l] r2b,i2b
    float* lgs  = (float*)(L + 65536);     // 256 floats: logits
    float* wfl  = (float*)(L + 66560);     // 256 floats: softmax weights
    float* wred = (float*)(L + 67584);     // 8 floats: cross-wave reduce

    const int t     = threadIdx.x;
    const int b     = blockIdx.x;
    const int w     = t >> 6;
    const int lane  = t & 63;
    const int l15   = lane & 15;
    const int koff8 = (lane >> 4) * 8;     // element offset of lane's k-group
    const int koffb = koff8 * 2;           // byte offset (bf16)
    const int arow  = w * 16 + l15;        // this wave's A-rows (l)
    const int lb    = w * 16 + (lane >> 4) * 4;  // C-row base (l)

    // ---- A-fragments: X direct from global, split in-reg ----
    bf16x8 axh[2][4], axl[2][4];
    {
        const float* xs[2] = {xr, xi};
#pragma unroll
        for (int arr = 0; arr < 2; ++arr)
#pragma unroll
            for (int ks = 0; ks < 4; ++ks) {
                const float* p = xs[arr] + (size_t)(b * NL + arow) * ND + ks * 32 + koff8;
                F4 f0, f1;
                f0.v = *(const float4*)&p[0];
                f1.v = *(const float4*)&p[4];
                bf16x8 h, l;
#pragma unroll
                for (int e = 0; e < 4; ++e) {
                    short2 s = bsplit(f0.f[e]); h[e] = s.x; l[e] = s.y;
                }
#pragma unroll
                for (int e = 0; e < 4; ++e) {
                    short2 s = bsplit(f1.f[e]); h[4 + e] = s.x; l[4 + e] = s.y;
                }
                axh[arr][ks] = h;
                axl[arr][ks] = l;
            }
    }

    // ---- proj MFMA: acc[mat][nt], B-frags direct from pre-split W ----
    f32x4 acc[4][8];
#pragma unroll
    for (int m = 0; m < 4; ++m)
#pragma unroll
        for (int nt = 0; nt < 8; ++nt) acc[m][nt] = (f32x4){0.f, 0.f, 0.f, 0.f};

#pragma unroll
    for (int mat = 0; mat < 4; ++mat) {
        const int arr = mat & 1;
#pragma unroll
        for (int nt = 0; nt < 8; ++nt) {
            const ushort* wp = whg + mat * 16384 + (nt * 16 + l15) * 128 + koff8;
            const ushort* lp = wlg + mat * 16384 + (nt * 16 + l15) * 128 + koff8;
#pragma unroll
            for (int ks = 0; ks < 4; ++ks) {
                bf16x8 bh = *(const bf16x8*)&wp[ks * 32];
                bf16x8 bl = *(const bf16x8*)&lp[ks * 32];
                acc[mat][nt] = __builtin_amdgcn_mfma_f32_16x16x32_bf16(axh[arr][ks], bh, acc[mat][nt], 0, 0, 0);
                acc[mat][nt] = __builtin_amdgcn_mfma_f32_16x16x32_bf16(axh[arr][ks], bl, acc[mat][nt], 0, 0, 0);
                acc[mat][nt] = __builtin_amdgcn_mfma_f32_16x16x32_bf16(axl[arr][ks], bh, acc[mat][nt], 0, 0, 0);
            }
        }
    }

    // ---- epilogue: bias, logit partials, G writes (r8-verified layout) ----
    float pR[4] = {0.f, 0.f, 0.f, 0.f};
    float pI[4] = {0.f, 0.f, 0.f, 0.f};
#pragma unroll
    for (int nt = 0; nt < 8; ++nt) {
        const int d = nt * 16 + l15;
        const float b0 = br1[d], b1 = bi1[d], b2 = br2[d], b3 = bi2[d];
        ushort g2[4], g3[4];
#pragma unroll
        for (int r = 0; r < 4; ++r) {
            float y0 = acc[0][nt][r] + b0;
            float y1 = acc[1][nt][r] + b1;
            float y2 = acc[2][nt][r] + b2;
            float y3 = acc[3][nt][r] + b3;
            pR[r] += (y0 * y0 - y1 * y1) * (y2 * y2 - y3 * y3);
            pI[r] += 4.f * y0 * y1 * y2 * y3;
            g2[r] = f2bf(y2);
            g3[r] = f2bf(y3);
        }
        const int byte0 = d * 256 + ((lb * 2) ^ ((d & 7) << 4));
        *(unsigned int*)(Gm + byte0)             = (unsigned int)g2[0] | ((unsigned int)g2[1] << 16);
        *(unsigned int*)(Gm + byte0 + 4)         = (unsigned int)g2[2] | ((unsigned int)g2[3] << 16);
        *(unsigned int*)(Gm + 32768 + byte0)     = (unsigned int)g3[0] | ((unsigned int)g3[1] << 16);
        *(unsigned int*)(Gm + 32768 + byte0 + 4) = (unsigned int)g3[2] | ((unsigned int)g3[3] << 16);
    }

#pragma unroll
    for (int off = 1; off < 16; off <<= 1)
#pragma unroll
        for (int r = 0; r < 4; ++r) {
            pR[r] += __shfl_xor(pR[r], off);
            pI[r] += __shfl_xor(pI[r], off);
        }
    if (l15 == 0) {
#pragma unroll
        for (int r = 0; r < 4; ++r) {
            lgs[lb + r]       = pR[r];
            lgs[128 + lb + r] = pI[r];
        }
    }
    __syncthreads();

    // ---- softmax (waves 0-3): full weights wfl (no sqrt) ----
    float sv = 0.f, se = 0.f;
    const int c = t >> 7;
    if (t < 256) {
        sv = lgs[c * 128 + (t & 127)];
        float m = sv;
#pragma unroll
        for (int off = 1; off < 64; off <<= 1) m = fmaxf(m, __shfl_xor(m, off));
        if (lane == 0) wred[t >> 6] = m;
    }
    __syncthreads();
    if (t < 256) {
        float m = fmaxf(wred[c * 2], wred[c * 2 + 1]);
        se = expf(sv - m);
        float s = se;
#pragma unroll
        for (int off = 1; off < 64; off <<= 1) s += __shfl_xor(s, off);
        if (lane == 0) wred[4 + (t >> 6)] = s;
    }
    __syncthreads();
    if (t < 256) {
        float s = wred[4 + c * 2] + wred[4 + c * 2 + 1];
        wfl[c * 128 + (t & 127)] = se / s;
    }
    __syncthreads();

    // ---- gram: wave = (term = w>>2, m-tiles (w&3)*2 + {0,1}) ----
    const int term = w >> 2;
    const int mt0  = (w & 3) * 2;

    f32x4 accP[2][8], accN[2][8];
#pragma unroll
    for (int m = 0; m < 2; ++m)
#pragma unroll
        for (int nt = 0; nt < 8; ++nt) {
            accP[m][nt] = (f32x4){0.f, 0.f, 0.f, 0.f};
            accN[m][nt] = (f32x4){0.f, 0.f, 0.f, 0.f};
        }

#pragma unroll
    for (int ks = 0; ks < 4; ++ks) {
        // weight slice for this lane's k-group (8 l's)
        F4 w0, w1;
        w0.v = *(const float4*)&wfl[term * 128 + ks * 32 + koff8];
        w1.v = *(const float4*)&wfl[term * 128 + ks * 32 + koff8 + 4];
        float wv[8] = {w0.f[0], w0.f[1], w0.f[2], w0.f[3],
                       w1.f[0], w1.f[1], w1.f[2], w1.f[3]};

        bf16x8 aP[2], aN[2];
#pragma unroll
        for (int m = 0; m < 2; ++m) {
            const int ar = (mt0 + m) * 16 + l15;
            const int ab = ar * 256 + (((ks * 64) + koffb) ^ ((ar & 7) << 4));
            BF8 a0; a0.v = *(const bf16x8*)(Gm + ab);
            BF8 a1; a1.v = *(const bf16x8*)(Gm + 32768 + ab);
            bf16x8 s0, s1;
#pragma unroll
            for (int e = 0; e < 8; ++e) {
                s0[e] = (short)f2bf(bf2f(a0.u[e]) * wv[e]);
                s1[e] = (short)f2bf(bf2f(a1.u[e]) * wv[e]);
            }
            aP[m] = term ? s1 : s0;   // R: wr.r2 ; I: wi.i2
            aN[m] = term ? s0 : s1;   // R: wr.i2 ; I: wi.r2
        }
#pragma unroll
        for (int nt = 0; nt < 8; ++nt) {
            const int br = nt * 16 + l15;
            const int bb = br * 256 + (((ks * 64) + koffb) ^ ((br & 7) << 4));
            bf16x8 b0 = *(const bf16x8*)(Gm + bb);            // raw r2
            bf16x8 b1 = *(const bf16x8*)(Gm + 32768 + bb);    // raw i2
#pragma unroll
            for (int m = 0; m < 2; ++m) {
                accP[m][nt] = __builtin_amdgcn_mfma_f32_16x16x32_bf16(aP[m], b0, accP[m][nt], 0, 0, 0);
                accN[m][nt] = __builtin_amdgcn_mfma_f32_16x16x32_bf16(aN[m], b1, accN[m][nt], 0, 0, 0);
            }
        }
    }

    const float sgn = term ? 1.f : -1.f;
    float* dst = out + (size_t)term * NB * ND * ND + (size_t)b * ND * ND;
#pragma unroll
    for (int m = 0; m < 2; ++m) {
        const int rb = (mt0 + m) * 16 + (lane >> 4) * 4;
#pragma unroll
        for (int nt = 0; nt < 8; ++nt) {
            const int ec = nt * 16 + l15;
#pragma unroll
            for (int r = 0; r < 4; ++r)
                dst[(size_t)(rb + r) * ND + ec] = accP[m][nt][r] + sgn * accN[m][nt][r];
        }
    }
}

extern "C" void kernel_launch(void* const* d_in, const int* in_sizes, int n_in,
                              void* d_out, int out_size, void* d_ws, size_t ws_size,
                              hipStream_t stream)
{
    const float* xr  = (const float*)d_in[0];
    const float* xi  = (const float*)d_in[1];
    const float* Wr1 = (const float*)d_in[2];
    const float* br1 = (const float*)d_in[3];
    const float* Wi1 = (const float*)d_in[4];
    const float* bi1 = (const float*)d_in[5];
    const float* Wr2 = (const float*)d_in[6];
    const float* br2 = (const float*)d_in[7];
    const float* Wi2 = (const float*)d_in[8];
    const float* bi2 = (const float*)d_in[9];

    ushort* whg = (ushort*)d_ws;            // [4][128][128] bf16 hi
    ushort* wlg = whg + 4 * 16384;          // [4][128][128] bf16 lo

    (void)hipFuncSetAttribute((const void*)k_fused,
                              hipFuncAttributeMaxDynamicSharedMemorySize, 67648);

    hipLaunchKernelGGL(k_wsplit, dim3(64), dim3(256), 0, stream,
                       Wr1, Wi1, Wr2, Wi2, whg, wlg);
    hipLaunchKernelGGL(k_fused, dim3(NB), dim3(512), 67648, stream,
                       xr, xi, whg, wlg, br1, bi1, br2, bi2,
                       (float*)d_out);
}